// Round 6
// baseline (709.427 us; speedup 1.0000x reference)
//
#include <hip/hip_runtime.h>
#include <math.h>

#define BB 4
#define SS 4096
#define DD 1024
#define TPp 16
#define TEe 64
#define DKk 128

typedef __attribute__((ext_vector_type(8))) short short8;
typedef __attribute__((ext_vector_type(4))) float floatx4;
typedef __attribute__((ext_vector_type(16))) float floatx16;

#define BSTRIDE 524288   // 4096*128 shorts per batch for frag-layout arrays
#define WFRAG 131072     // shorts per weight matrix in B-frag layout (1024x128)

// bf16 helpers (RNE, branchless)
static __device__ inline short f2bf(float f) {
  union { float f; unsigned u; } v; v.f = f;
  unsigned r = v.u + 0x7fff + ((v.u >> 16) & 1);
  return (short)(r >> 16);
}
static __device__ inline float bf2f(short s) {
  union { unsigned u; float f; } v; v.u = ((unsigned)(unsigned short)s) << 16;
  return v.f;
}

// ---------------- Kernel A1: E = tp@Wt + bt ; T_scaled ; bqt = bq@T ----------------
__global__ __launch_bounds__(256) void temb_kernel(const float* __restrict__ tp,
                                                   const float* __restrict__ Wt,
                                                   const float* __restrict__ bt,
                                                   const float* __restrict__ bq,
                                                   float* __restrict__ Tws,
                                                   float* __restrict__ bqtws) {
  __shared__ float sE[TPp * DKk];
  __shared__ float sB[TPp];
  __shared__ float red[256];
  const int p = blockIdx.x, b = blockIdx.y;
  const int tid = threadIdx.x;
  float lsq = 0.f;
  for (int l = 0; l < 8; ++l) {
    int idx = tid + 256 * l;
    int i = idx >> 7, j = idx & 127;
    float a = bt[j];
    for (int c = 0; c < TEe; ++c)
      a += tp[((size_t)b * TPp + i) * TEe + c] * Wt[c * DKk + j];
    sE[idx] = a;
    lsq += a * a;
  }
  red[tid] = lsq;
  __syncthreads();
  for (int s2 = 128; s2 > 0; s2 >>= 1) {
    if (tid < s2) red[tid] += red[tid + s2];
    __syncthreads();
  }
  const float total = red[0];
  const float scale = (float)SS / (sqrtf((float)SS * total) + 1e-8f);
  if (tid < TPp) {
    float a = 0.f;
    for (int d2 = 0; d2 < DKk; ++d2) a += bq[d2] * sE[tid * DKk + d2];
    sB[tid] = a;
  }
  __syncthreads();
  for (int l = 0; l < 8; ++l) {
    int idx = p * 2048 + tid + 256 * l;
    int d2 = idx >> 7, e = idx & 127;
    float a = 0.f;
    #pragma unroll
    for (int t = 0; t < TPp; ++t) a += sE[t * DKk + d2] * sE[t * DKk + e];
    Tws[(size_t)b * DKk * DKk + idx] = scale * a;
  }
  if (p == 0 && tid < DKk) {
    float a = 0.f;
    #pragma unroll
    for (int t = 0; t < TPp; ++t) a += sB[t] * sE[t * DKk + tid];
    bqtws[b * DKk + tid] = scale * a;
  }
}

// ---------------- Kernel A2: Wqp[b] = Wq @ T[b], written directly as hi/lo B-frags --
__global__ __launch_bounds__(128) void wqp_kernel(const float* __restrict__ Wq,
                                                  const float* __restrict__ Tws,
                                                  short* __restrict__ WqphF,
                                                  short* __restrict__ WqplF) {
  __shared__ float sW[DKk];
  const int m = blockIdx.x, b = blockIdx.y;   // m = k-index of Wqp
  const int e = threadIdx.x;                  // n-index
  sW[e] = Wq[(size_t)m * DKk + e];
  __syncthreads();
  const float* Tb = Tws + (size_t)b * DKk * DKk;
  float a = 0.f;
  #pragma unroll 8
  for (int d2 = 0; d2 < DKk; ++d2) a += sW[d2] * Tb[d2 * DKk + e];
  const size_t off = (size_t)b * WFRAG +
      (size_t)((e >> 5) * 64 + (m >> 4)) * 512 + (32 * ((m >> 3) & 1) + (e & 31)) * 8 +
      (m & 7);
  short hh = f2bf(a);
  WqphF[off] = hh;
  WqplF[off] = f2bf(a - bf2f(hh));
}

// ---------------- Kernel A3: Wk/Wv -> hi/lo B-frags ----------------
__global__ __launch_bounds__(256) void wcast_kernel(const float* __restrict__ Wk,
                                                    const float* __restrict__ Wv,
                                                    short* __restrict__ WkhF,
                                                    short* __restrict__ WklF,
                                                    short* __restrict__ WvhF,
                                                    short* __restrict__ WvlF) {
  const float* W = blockIdx.y ? Wv : Wk;
  short* H = blockIdx.y ? WvhF : WkhF;
  short* L = blockIdx.y ? WvlF : WklF;
  const int ks = blockIdx.x;                     // 0..63
  const int wave = threadIdx.x >> 6, lane = threadIdx.x & 63;
  const int n = wave * 32 + (lane & 31);
  const int k0 = ks * 16 + (lane >> 5) * 8;
  short8 h, l;
  #pragma unroll
  for (int j = 0; j < 8; ++j) {
    float v = W[(size_t)(k0 + j) * DKk + n];
    short hh = f2bf(v);
    h[j] = hh;
    l[j] = f2bf(v - bf2f(hh));
  }
  const size_t off = ((size_t)wave * 64 + ks) * 512 + lane * 8;
  *(short8*)&H[off] = h;
  *(short8*)&L[off] = l;
}

// ---------------- Kernel B: fused MFMA projection (split bf16, 3 regions/block) -----
__global__ __launch_bounds__(256, 2) void proj_kernel(const float* __restrict__ x,
                                                      const short* __restrict__ WqphF,
                                                      const short* __restrict__ WqplF,
                                                      const short* __restrict__ WkhF,
                                                      const short* __restrict__ WklF,
                                                      const short* __restrict__ WvhF,
                                                      const short* __restrict__ WvlF,
                                                      const float* __restrict__ bqt,
                                                      const float* __restrict__ bk,
                                                      const float* __restrict__ bv,
                                                      short* __restrict__ QTh,
                                                      short* __restrict__ QTl,
                                                      short* __restrict__ Kh,
                                                      short* __restrict__ Kl,
                                                      short* __restrict__ VT) {
  __shared__ float xs[32 * 66];   // 32 rows x 64 k
  const int tileG = blockIdx.x;             // 0..511
  const int b = tileG >> 7, tileL = tileG & 127;
  const int rowbase = tileG * 32;
  const int tid = threadIdx.x, wave = tid >> 6, lane = tid & 63;
  const int l31 = lane & 31, half = lane >> 5;
  const short* B0h = WqphF + (size_t)b * WFRAG + (size_t)wave * 32768;
  const short* B0l = WqplF + (size_t)b * WFRAG + (size_t)wave * 32768;
  const short* B1h = WkhF + (size_t)wave * 32768;
  const short* B1l = WklF + (size_t)wave * 32768;
  const short* B2h = WvhF + (size_t)wave * 32768;
  const short* B2l = WvlF + (size_t)wave * 32768;
  floatx16 acc0, acc1, acc2;
  #pragma unroll
  for (int r = 0; r < 16; ++r) { acc0[r] = 0.f; acc1[r] = 0.f; acc2[r] = 0.f; }
  const int sr = tid >> 3, sc = (tid & 7) * 8;
  const float* xrow = &x[(size_t)(rowbase + sr) * DD + sc];
  float4 p0 = *(const float4*)xrow;
  float4 p1 = *(const float4*)(xrow + 4);
  for (int kc = 0; kc < 16; ++kc) {
    __syncthreads();
    float* dst = &xs[sr * 66 + sc];
    dst[0] = p0.x; dst[1] = p0.y; dst[2] = p0.z; dst[3] = p0.w;
    dst[4] = p1.x; dst[5] = p1.y; dst[6] = p1.z; dst[7] = p1.w;
    if (kc < 15) {
      p0 = *(const float4*)(xrow + (kc + 1) * 64);
      p1 = *(const float4*)(xrow + (kc + 1) * 64 + 4);
    }
    __syncthreads();
    #pragma unroll
    for (int ks = 0; ks < 4; ++ks) {
      const float* ap = &xs[l31 * 66 + ks * 16 + half * 8];
      short8 aH, aL;
      #pragma unroll
      for (int j = 0; j < 8; ++j) {
        float v = ap[j];
        short hh = f2bf(v);
        aH[j] = hh;
        aL[j] = f2bf(v - bf2f(hh));
      }
      const size_t boff = (size_t)(kc * 4 + ks) * 512 + lane * 8;
      short8 bh, bl;
      bh = *(const short8*)(B0h + boff); bl = *(const short8*)(B0l + boff);
      acc0 = __builtin_amdgcn_mfma_f32_32x32x16_bf16(aL, bh, acc0, 0, 0, 0);
      acc0 = __builtin_amdgcn_mfma_f32_32x32x16_bf16(aH, bl, acc0, 0, 0, 0);
      acc0 = __builtin_amdgcn_mfma_f32_32x32x16_bf16(aH, bh, acc0, 0, 0, 0);
      bh = *(const short8*)(B1h + boff); bl = *(const short8*)(B1l + boff);
      acc1 = __builtin_amdgcn_mfma_f32_32x32x16_bf16(aL, bh, acc1, 0, 0, 0);
      acc1 = __builtin_amdgcn_mfma_f32_32x32x16_bf16(aH, bl, acc1, 0, 0, 0);
      acc1 = __builtin_amdgcn_mfma_f32_32x32x16_bf16(aH, bh, acc1, 0, 0, 0);
      bh = *(const short8*)(B2h + boff); bl = *(const short8*)(B2l + boff);
      acc2 = __builtin_amdgcn_mfma_f32_32x32x16_bf16(aL, bh, acc2, 0, 0, 0);
      acc2 = __builtin_amdgcn_mfma_f32_32x32x16_bf16(aH, bl, acc2, 0, 0, 0);
      acc2 = __builtin_amdgcn_mfma_f32_32x32x16_bf16(aH, bh, acc2, 0, 0, 0);
    }
  }
  // Epilogue. C/D: col(n) = lane&31 (+32*wave), row(t) = (reg&3)+8*(reg>>2)+4*half.
  const int f = wave * 32 + l31;
  const int fks = f >> 4, fh = (f >> 3) & 1, fj = f & 7;
  const size_t qkbase =
      (size_t)b * BSTRIDE + (size_t)tileL * 4096 + (size_t)fks * 512 + fj;
  const float biasq = bqt[b * DKk + f];
  const float biask = bk[f];
  #pragma unroll
  for (int reg = 0; reg < 16; ++reg) {
    const int t = (reg & 3) + 8 * (reg >> 2) + 4 * half;
    const size_t off = qkbase + (size_t)(fh * 32 + t) * 8;
    float v = acc0[reg] + biasq;
    short hh = f2bf(v);
    QTh[off] = hh;
    QTl[off] = f2bf(v - bf2f(hh));
    v = acc1[reg] + biask;
    hh = f2bf(v);
    Kh[off] = hh;
    Kl[off] = f2bf(v - bf2f(hh));
  }
  // V epilogue -> 32x32x16 B-operand layout over [t][d]:
  // off(t,d) = ((d>>5)*256 + (t>>4))*512 + (((t>>3)&1)*32 + (d&31))*8 + (t&7)
  const float biasv = bv[f];
  #pragma unroll
  for (int g = 0; g < 4; ++g) {
    short4 s4;
    s4.x = f2bf(acc2[4 * g + 0] + biasv);
    s4.y = f2bf(acc2[4 * g + 1] + biasv);
    s4.z = f2bf(acc2[4 * g + 2] + biasv);
    s4.w = f2bf(acc2[4 * g + 3] + biasv);
    const size_t off = (size_t)b * BSTRIDE +
        (size_t)(wave * 256 + tileL * 2 + (g >> 1)) * 512 +
        (size_t)((g & 1) * 32 + l31) * 8 + 4 * half;
    *(short4*)&VT[off] = s4;
  }
}

// ---------------- Kernel C1: m/l only (no attn write). Transposed tiles: A=K, B=QT.
// D[m=t][n=q]: lane owns q=lane&31 -> per-lane scalar online m/l.
__global__ __launch_bounds__(256, 2) void ml_kernel(const short* __restrict__ QTh,
                                                    const short* __restrict__ QTl,
                                                    const short* __restrict__ Kh,
                                                    const short* __restrict__ Kl,
                                                    float* __restrict__ mrow,
                                                    float* __restrict__ linv) {
  __shared__ float smM[4][32], smL[4][32];
  const int id = blockIdx.x;
  const int xcd = id & 7;
  const int b = xcd >> 1;
  const int tile = ((id >> 3) << 1) + (xcd & 1);   // 0..127
  const int rowbase = tile * 32;
  const int tid = threadIdx.x;
  const int wave = tid >> 6, lane = tid & 63;
  const int l31 = lane & 31;
  const float sc = 0.088388347648318447f;  // 1/sqrt(128)
  const size_t qbase = (size_t)b * BSTRIDE + (size_t)tile * 4096 + lane * 8;
  short8 qh[8], ql[8];
  #pragma unroll
  for (int ks = 0; ks < 8; ++ks) {
    qh[ks] = *(const short8*)(QTh + qbase + ks * 512);
    ql[ks] = *(const short8*)(QTl + qbase + ks * 512);
  }
  float m = -INFINITY, l = 0.f;
  for (int ct = wave; ct < 128; ct += 4) {
    const size_t kbase = (size_t)b * BSTRIDE + (size_t)ct * 4096 + lane * 8;
    floatx16 acc;
    #pragma unroll
    for (int r = 0; r < 16; ++r) acc[r] = 0.f;
    #pragma unroll
    for (int ks = 0; ks < 8; ++ks) {
      short8 kh = *(const short8*)(Kh + kbase + ks * 512);
      short8 kl = *(const short8*)(Kl + kbase + ks * 512);
      acc = __builtin_amdgcn_mfma_f32_32x32x16_bf16(kh, qh[ks], acc, 0, 0, 0);
      acc = __builtin_amdgcn_mfma_f32_32x32x16_bf16(kh, ql[ks], acc, 0, 0, 0);
      acc = __builtin_amdgcn_mfma_f32_32x32x16_bf16(kl, qh[ks], acc, 0, 0, 0);
    }
    float s[16];
    float tmax = -INFINITY;
    #pragma unroll
    for (int r = 0; r < 16; ++r) { s[r] = acc[r] * sc; tmax = fmaxf(tmax, s[r]); }
    const float mn = fmaxf(m, tmax);
    float ps = 0.f;
    #pragma unroll
    for (int r = 0; r < 16; ++r) ps += __expf(s[r] - mn);
    l = l * __expf(m - mn) + ps;
    m = mn;
  }
  // combine halves (q identical across halves)
  {
    const float mo = __shfl_xor(m, 32, 64);
    const float lo = __shfl_xor(l, 32, 64);
    const float mn = fmaxf(m, mo);
    l = l * __expf(m - mn) + lo * __expf(mo - mn);
    m = mn;
  }
  if (lane < 32) { smM[wave][l31] = m; smL[wave][l31] = l; }
  __syncthreads();
  if (tid < 32) {
    float mm = smM[0][tid], ll = smL[0][tid];
    #pragma unroll
    for (int w = 1; w < 4; ++w) {
      const float mo = smM[w][tid], lo = smL[w][tid];
      const float mn = fmaxf(mm, mo);
      ll = ll * __expf(mm - mn) + lo * __expf(mo - mn);
      mm = mn;
    }
    mrow[b * SS + rowbase + tid] = mm;
    linv[b * SS + rowbase + tid] = 1.0f / ll;
  }
}

// ---------------- Kernel C2: recompute scores, write p once (nt), P@V MFMA ----------
// Same transposed tile (bitwise-identical MFMA sequence as ml_kernel). Lane owns
// q = lane&31. C->A frag for PV via xor-32 half swap. attn written exactly once.
__global__ __launch_bounds__(256, 2) void pv_kernel(const short* __restrict__ QTh,
                                                    const short* __restrict__ QTl,
                                                    const short* __restrict__ Kh,
                                                    const short* __restrict__ Kl,
                                                    const short* __restrict__ VT,
                                                    float* __restrict__ attn,
                                                    const float* __restrict__ mrow,
                                                    const float* __restrict__ linv,
                                                    float* __restrict__ outp) {
  __shared__ float sAcc[3][4][64][16];  // 48 KB partial-out exchange
  const int id = blockIdx.x;
  const int xcd = id & 7;
  const int b = xcd >> 1;
  const int tile = ((id >> 3) << 1) + (xcd & 1);   // 0..127
  const int rowbase = tile * 32;
  const int tid = threadIdx.x;
  const int wave = tid >> 6, lane = tid & 63;
  const int l31 = lane & 31, half = lane >> 5;
  const float sc = 0.088388347648318447f;
  const size_t qbase = (size_t)b * BSTRIDE + (size_t)tile * 4096 + lane * 8;
  short8 qh[8], ql[8];
  #pragma unroll
  for (int ks = 0; ks < 8; ++ks) {
    qh[ks] = *(const short8*)(QTh + qbase + ks * 512);
    ql[ks] = *(const short8*)(QTl + qbase + ks * 512);
  }
  const float m_i = mrow[b * SS + rowbase + l31];
  const float li = linv[b * SS + rowbase + l31];
  float* arow = attn + (size_t)b * SS * SS + (size_t)(rowbase + l31) * SS + 4 * half;
  const short* vtb = VT + (size_t)b * BSTRIDE + lane * 8;
  floatx16 pacc[4];
  #pragma unroll
  for (int dt = 0; dt < 4; ++dt)
    #pragma unroll
    for (int r = 0; r < 16; ++r) pacc[dt][r] = 0.f;
  for (int ct = wave; ct < 128; ct += 4) {
    const size_t kbase = (size_t)b * BSTRIDE + (size_t)ct * 4096 + lane * 8;
    floatx16 acc;
    #pragma unroll
    for (int r = 0; r < 16; ++r) acc[r] = 0.f;
    #pragma unroll
    for (int ks = 0; ks < 8; ++ks) {
      short8 kh = *(const short8*)(Kh + kbase + ks * 512);
      short8 kl = *(const short8*)(Kl + kbase + ks * 512);
      acc = __builtin_amdgcn_mfma_f32_32x32x16_bf16(kh, qh[ks], acc, 0, 0, 0);
      acc = __builtin_amdgcn_mfma_f32_32x32x16_bf16(kh, ql[ks], acc, 0, 0, 0);
      acc = __builtin_amdgcn_mfma_f32_32x32x16_bf16(kl, qh[ks], acc, 0, 0, 0);
    }
    float p[16];
    #pragma unroll
    for (int r = 0; r < 16; ++r) p[r] = __expf(acc[r] * sc - m_i) * li;
    // store p: lane owns row q=l31; regs 4g..4g+3 are t' = 8g + 4*half + 0..3
    #pragma unroll
    for (int g = 0; g < 4; ++g) {
      floatx4 o = {p[4 * g], p[4 * g + 1], p[4 * g + 2], p[4 * g + 3]};
      __builtin_nontemporal_store(o, (floatx4*)(arow + ct * 32 + 8 * g));
    }
    // C->A frags (k = t): af0 covers t'=0..15, af1 covers t'=16..31
    short8 af0, af1;
    #pragma unroll
    for (int rr = 0; rr < 4; ++rr) {
      const float shl = __shfl_xor(p[rr], 32, 64);
      const float shh = __shfl_xor(p[rr + 4], 32, 64);
      af0[rr] = f2bf(half ? shh : p[rr]);
      af0[rr + 4] = f2bf(half ? p[rr + 4] : shl);
      const float shl2 = __shfl_xor(p[rr + 8], 32, 64);
      const float shh2 = __shfl_xor(p[rr + 12], 32, 64);
      af1[rr] = f2bf(half ? shh2 : p[rr + 8]);
      af1[rr + 4] = f2bf(half ? p[rr + 12] : shl2);
    }
    #pragma unroll
    for (int dt = 0; dt < 4; ++dt) {
      short8 v0 = *(const short8*)(vtb + (size_t)(dt * 256 + ct * 2) * 512);
      pacc[dt] = __builtin_amdgcn_mfma_f32_32x32x16_bf16(af0, v0, pacc[dt], 0, 0, 0);
      short8 v1 = *(const short8*)(vtb + (size_t)(dt * 256 + ct * 2 + 1) * 512);
      pacc[dt] = __builtin_amdgcn_mfma_f32_32x32x16_bf16(af1, v1, pacc[dt], 0, 0, 0);
    }
  }
  if (wave > 0) {
    #pragma unroll
    for (int dt = 0; dt < 4; ++dt)
      #pragma unroll
      for (int r = 0; r < 16; ++r) sAcc[wave - 1][dt][lane][r] = pacc[dt][r];
  }
  __syncthreads();
  if (wave == 0) {
    #pragma unroll
    for (int dt = 0; dt < 4; ++dt)
      #pragma unroll
      for (int r = 0; r < 16; ++r) {
        const int q = (r & 3) + 8 * (r >> 2) + 4 * half;
        const float v = pacc[dt][r] + sAcc[0][dt][lane][r] + sAcc[1][dt][lane][r] +
                        sAcc[2][dt][lane][r];
        outp[((size_t)b * SS + rowbase + q) * DKk + dt * 32 + l31] = v;
      }
  }
}

extern "C" void kernel_launch(void* const* d_in, const int* in_sizes, int n_in,
                              void* d_out, int out_size, void* d_ws, size_t ws_size,
                              hipStream_t stream) {
  const float* x  = (const float*)d_in[0];
  const float* tp = (const float*)d_in[1];
  const float* Wq = (const float*)d_in[2];
  const float* bq = (const float*)d_in[3];
  const float* Wk = (const float*)d_in[4];
  const float* bk = (const float*)d_in[5];
  const float* Wv = (const float*)d_in[6];
  const float* bv = (const float*)d_in[7];
  const float* Wt = (const float*)d_in[8];
  const float* bt = (const float*)d_in[9];
  float* out  = (float*)d_out;
  float* attn = out + (size_t)BB * SS * DKk;
  float* ws = (float*)d_ws;
  float* Tws   = ws;                          // 65536
  float* bqt   = ws + 65536;                  // 512
  short* WqphF = (short*)(ws + 66048);
  short* WqplF = (short*)(ws + 328192);
  short* WkhF  = (short*)(ws + 590336);
  short* WklF  = (short*)(ws + 655872);
  short* WvhF  = (short*)(ws + 721408);
  short* WvlF  = (short*)(ws + 786944);
  short* QTh   = (short*)(ws + 852480);
  short* QTl   = (short*)(ws + 1901056);
  short* Kh    = (short*)(ws + 2949632);
  short* Kl    = (short*)(ws + 3998208);
  short* VT    = (short*)(ws + 5046784);
  float* mrow  = ws + 6095360;
  float* lin   = ws + 6111744;                // total 6128128 fl = 24.5 MiB

  temb_kernel<<<dim3(8, 4), 256, 0, stream>>>(tp, Wt, bt, bq, Tws, bqt);
  wqp_kernel<<<dim3(1024, 4), 128, 0, stream>>>(Wq, Tws, WqphF, WqplF);
  wcast_kernel<<<dim3(64, 2), 256, 0, stream>>>(Wk, Wv, WkhF, WklF, WvhF, WvlF);
  proj_kernel<<<512, 256, 0, stream>>>(x, WqphF, WqplF, WkhF, WklF, WvhF, WvlF,
                                       bqt, bk, bv, QTh, QTl, Kh, Kl, VT);
  ml_kernel<<<512, 256, 0, stream>>>(QTh, QTl, Kh, Kl, mrow, lin);
  pv_kernel<<<512, 256, 0, stream>>>(QTh, QTl, Kh, Kl, VT, attn, mrow, lin, out);
}

// Round 7
// 620.039 us; speedup vs baseline: 1.1442x; 1.1442x over previous
//
#include <hip/hip_runtime.h>
#include <math.h>

#define BB 4
#define SS 4096
#define DD 1024
#define TPp 16
#define TEe 64
#define DKk 128

typedef __attribute__((ext_vector_type(8))) short short8;
typedef __attribute__((ext_vector_type(4))) float floatx4;
typedef __attribute__((ext_vector_type(16))) float floatx16;

#define BSTRIDE 524288   // 4096*128 shorts per batch for frag-layout arrays
#define WFRAG 131072     // shorts per weight matrix in B-frag layout (1024x128)
#define XTILE 32768      // shorts per 32-row x tile in A-frag layout (32x1024)

// bf16 helpers (RNE, branchless)
static __device__ inline short f2bf(float f) {
  union { float f; unsigned u; } v; v.f = f;
  unsigned r = v.u + 0x7fff + ((v.u >> 16) & 1);
  return (short)(r >> 16);
}
static __device__ inline float bf2f(short s) {
  union { unsigned u; float f; } v; v.u = ((unsigned)(unsigned short)s) << 16;
  return v.f;
}

// ---------------- Kernel A1: E = tp@Wt + bt ; T_scaled ; bqt = bq@T ----------------
__global__ __launch_bounds__(256) void temb_kernel(const float* __restrict__ tp,
                                                   const float* __restrict__ Wt,
                                                   const float* __restrict__ bt,
                                                   const float* __restrict__ bq,
                                                   float* __restrict__ Tws,
                                                   float* __restrict__ bqtws) {
  __shared__ float sE[TPp * DKk];
  __shared__ float sB[TPp];
  __shared__ float red[256];
  const int p = blockIdx.x, b = blockIdx.y;
  const int tid = threadIdx.x;
  float lsq = 0.f;
  for (int l = 0; l < 8; ++l) {
    int idx = tid + 256 * l;
    int i = idx >> 7, j = idx & 127;
    float a = bt[j];
    for (int c = 0; c < TEe; ++c)
      a += tp[((size_t)b * TPp + i) * TEe + c] * Wt[c * DKk + j];
    sE[idx] = a;
    lsq += a * a;
  }
  red[tid] = lsq;
  __syncthreads();
  for (int s2 = 128; s2 > 0; s2 >>= 1) {
    if (tid < s2) red[tid] += red[tid + s2];
    __syncthreads();
  }
  const float total = red[0];
  const float scale = (float)SS / (sqrtf((float)SS * total) + 1e-8f);
  if (tid < TPp) {
    float a = 0.f;
    for (int d2 = 0; d2 < DKk; ++d2) a += bq[d2] * sE[tid * DKk + d2];
    sB[tid] = a;
  }
  __syncthreads();
  for (int l = 0; l < 8; ++l) {
    int idx = p * 2048 + tid + 256 * l;
    int d2 = idx >> 7, e = idx & 127;
    float a = 0.f;
    #pragma unroll
    for (int t = 0; t < TPp; ++t) a += sE[t * DKk + d2] * sE[t * DKk + e];
    Tws[(size_t)b * DKk * DKk + idx] = scale * a;
  }
  if (p == 0 && tid < DKk) {
    float a = 0.f;
    #pragma unroll
    for (int t = 0; t < TPp; ++t) a += sB[t] * sE[t * DKk + tid];
    bqtws[b * DKk + tid] = scale * a;
  }
}

// ---------------- Kernel A2: Wqp[b] = Wq @ T[b], written directly as hi/lo B-frags --
__global__ __launch_bounds__(128) void wqp_kernel(const float* __restrict__ Wq,
                                                  const float* __restrict__ Tws,
                                                  short* __restrict__ WqphF,
                                                  short* __restrict__ WqplF) {
  __shared__ float sW[DKk];
  const int m = blockIdx.x, b = blockIdx.y;   // m = k-index of Wqp
  const int e = threadIdx.x;                  // n-index
  sW[e] = Wq[(size_t)m * DKk + e];
  __syncthreads();
  const float* Tb = Tws + (size_t)b * DKk * DKk;
  float a = 0.f;
  #pragma unroll 8
  for (int d2 = 0; d2 < DKk; ++d2) a += sW[d2] * Tb[d2 * DKk + e];
  const size_t off = (size_t)b * WFRAG +
      (size_t)((e >> 5) * 64 + (m >> 4)) * 512 + (32 * ((m >> 3) & 1) + (e & 31)) * 8 +
      (m & 7);
  short hh = f2bf(a);
  WqphF[off] = hh;
  WqplF[off] = f2bf(a - bf2f(hh));
}

// ---------------- Kernel A3: Wk/Wv -> hi/lo B-frags ----------------
__global__ __launch_bounds__(256) void wcast_kernel(const float* __restrict__ Wk,
                                                    const float* __restrict__ Wv,
                                                    short* __restrict__ WkhF,
                                                    short* __restrict__ WklF,
                                                    short* __restrict__ WvhF,
                                                    short* __restrict__ WvlF) {
  const float* W = blockIdx.y ? Wv : Wk;
  short* H = blockIdx.y ? WvhF : WkhF;
  short* L = blockIdx.y ? WvlF : WklF;
  const int ks = blockIdx.x;                     // 0..63
  const int wave = threadIdx.x >> 6, lane = threadIdx.x & 63;
  const int n = wave * 32 + (lane & 31);
  const int k0 = ks * 16 + (lane >> 5) * 8;
  short8 h, l;
  #pragma unroll
  for (int j = 0; j < 8; ++j) {
    float v = W[(size_t)(k0 + j) * DKk + n];
    short hh = f2bf(v);
    h[j] = hh;
    l[j] = f2bf(v - bf2f(hh));
  }
  const size_t off = ((size_t)wave * 64 + ks) * 512 + lane * 8;
  *(short8*)&H[off] = h;
  *(short8*)&L[off] = l;
}

// ---------------- Kernel A4: x -> split-bf16 A-frags (once, shared by 3 regions) ----
// A-frag layout per 32-row tile: off(t, k) = ks*512 + (khalf*32 + t)*8 + j
// with ks = k>>4, khalf = (k>>3)&1, j = k&7.
__global__ __launch_bounds__(256) void xcast_kernel(const float* __restrict__ x,
                                                    short* __restrict__ XAh,
                                                    short* __restrict__ XAl) {
  const int tileG = blockIdx.x;           // 0..511
  const int rowbase = tileG * 32;
  const int tid = threadIdx.x;
  const int t = tid & 31, khalf = (tid >> 5) & 1, w = tid >> 6;
  const size_t abase = (size_t)tileG * XTILE + (size_t)(tid & 63) * 8;
  const float* xr = x + (size_t)(rowbase + t) * DD + khalf * 8;
  #pragma unroll
  for (int it = 0; it < 16; ++it) {
    const int ks = it * 4 + w;
    float4 u0 = *(const float4*)(xr + ks * 16);
    float4 u1 = *(const float4*)(xr + ks * 16 + 4);
    const float v[8] = {u0.x, u0.y, u0.z, u0.w, u1.x, u1.y, u1.z, u1.w};
    short8 h, l;
    #pragma unroll
    for (int j = 0; j < 8; ++j) {
      short hh = f2bf(v[j]);
      h[j] = hh;
      l[j] = f2bf(v[j] - bf2f(hh));
    }
    *(short8*)&XAh[abase + (size_t)ks * 512] = h;
    *(short8*)&XAl[abase + (size_t)ks * 512] = l;
  }
}

// ---------------- Kernel B: streaming MFMA projection, one region per block --------
// Grid 1536: region = id>>9 (0:QT 1:K 2:V), tileG = id&511. No LDS, dual acc chains.
__global__ __launch_bounds__(256, 4) void proj_kernel(const short* __restrict__ XAh,
                                                      const short* __restrict__ XAl,
                                                      const short* __restrict__ WqphF,
                                                      const short* __restrict__ WqplF,
                                                      const short* __restrict__ WkhF,
                                                      const short* __restrict__ WklF,
                                                      const short* __restrict__ WvhF,
                                                      const short* __restrict__ WvlF,
                                                      const float* __restrict__ bqt,
                                                      const float* __restrict__ bk,
                                                      const float* __restrict__ bv,
                                                      short* __restrict__ QTh,
                                                      short* __restrict__ QTl,
                                                      short* __restrict__ Kh,
                                                      short* __restrict__ Kl,
                                                      short* __restrict__ VT) {
  const int id = blockIdx.x;
  const int region = id >> 9, tileG = id & 511;
  const int b = tileG >> 7, tileL = tileG & 127;
  const int tid = threadIdx.x, wave = tid >> 6, lane = tid & 63;
  const int l31 = lane & 31, half = lane >> 5;
  const short* BH;
  const short* BL;
  if (region == 0)      { BH = WqphF + (size_t)b * WFRAG; BL = WqplF + (size_t)b * WFRAG; }
  else if (region == 1) { BH = WkhF; BL = WklF; }
  else                  { BH = WvhF; BL = WvlF; }
  BH += (size_t)wave * 32768 + (size_t)lane * 8;
  BL += (size_t)wave * 32768 + (size_t)lane * 8;
  const short* AH = XAh + (size_t)tileG * XTILE + (size_t)lane * 8;
  const short* AL = XAl + (size_t)tileG * XTILE + (size_t)lane * 8;
  floatx16 accE, accO;
  #pragma unroll
  for (int r = 0; r < 16; ++r) { accE[r] = 0.f; accO[r] = 0.f; }
  for (int ks = 0; ks < 64; ks += 2) {
    short8 a0h = *(const short8*)(AH + (size_t)ks * 512);
    short8 a0l = *(const short8*)(AL + (size_t)ks * 512);
    short8 b0h = *(const short8*)(BH + (size_t)ks * 512);
    short8 b0l = *(const short8*)(BL + (size_t)ks * 512);
    short8 a1h = *(const short8*)(AH + (size_t)(ks + 1) * 512);
    short8 a1l = *(const short8*)(AL + (size_t)(ks + 1) * 512);
    short8 b1h = *(const short8*)(BH + (size_t)(ks + 1) * 512);
    short8 b1l = *(const short8*)(BL + (size_t)(ks + 1) * 512);
    accE = __builtin_amdgcn_mfma_f32_32x32x16_bf16(a0l, b0h, accE, 0, 0, 0);
    accO = __builtin_amdgcn_mfma_f32_32x32x16_bf16(a1l, b1h, accO, 0, 0, 0);
    accE = __builtin_amdgcn_mfma_f32_32x32x16_bf16(a0h, b0l, accE, 0, 0, 0);
    accO = __builtin_amdgcn_mfma_f32_32x32x16_bf16(a1h, b1l, accO, 0, 0, 0);
    accE = __builtin_amdgcn_mfma_f32_32x32x16_bf16(a0h, b0h, accE, 0, 0, 0);
    accO = __builtin_amdgcn_mfma_f32_32x32x16_bf16(a1h, b1h, accO, 0, 0, 0);
  }
  floatx16 acc;
  #pragma unroll
  for (int r = 0; r < 16; ++r) acc[r] = accE[r] + accO[r];
  // Epilogue. C/D: col(n) = wave*32 + l31, row(t) = (reg&3)+8*(reg>>2)+4*half.
  const int f = wave * 32 + l31;
  if (region <= 1) {
    short* Hp = (region == 0) ? QTh : Kh;
    short* Lp = (region == 0) ? QTl : Kl;
    const float bias = (region == 0) ? bqt[b * DKk + f] : bk[f];
    const int fks = f >> 4, fh = (f >> 3) & 1, fj = f & 7;
    const size_t qkbase =
        (size_t)b * BSTRIDE + (size_t)tileL * 4096 + (size_t)fks * 512 + fj;
    #pragma unroll
    for (int reg = 0; reg < 16; ++reg) {
      const int t = (reg & 3) + 8 * (reg >> 2) + 4 * half;
      const size_t off = qkbase + (size_t)(fh * 32 + t) * 8;
      float v = acc[reg] + bias;
      short hh = f2bf(v);
      Hp[off] = hh;
      Lp[off] = f2bf(v - bf2f(hh));
    }
  } else {
    // V -> 32x32x16 B-operand layout over [t][d]:
    // off(t,d) = ((d>>5)*256 + (t>>4))*512 + (((t>>3)&1)*32 + (d&31))*8 + (t&7)
    const float biasv = bv[f];
    #pragma unroll
    for (int g = 0; g < 4; ++g) {
      short4 s4;
      s4.x = f2bf(acc[4 * g + 0] + biasv);
      s4.y = f2bf(acc[4 * g + 1] + biasv);
      s4.z = f2bf(acc[4 * g + 2] + biasv);
      s4.w = f2bf(acc[4 * g + 3] + biasv);
      const size_t off = (size_t)b * BSTRIDE +
          (size_t)(wave * 256 + tileL * 2 + (g >> 1)) * 512 +
          (size_t)((g & 1) * 32 + l31) * 8 + 4 * half;
      *(short4*)&VT[off] = s4;
    }
  }
}

// ---------------- Kernel C1: m/l only. Transposed tiles: A=K, B=QT; dual chains. ----
__global__ __launch_bounds__(256, 2) void ml_kernel(const short* __restrict__ QTh,
                                                    const short* __restrict__ QTl,
                                                    const short* __restrict__ Kh,
                                                    const short* __restrict__ Kl,
                                                    float* __restrict__ mrow,
                                                    float* __restrict__ linv) {
  __shared__ float smM[4][32], smL[4][32];
  const int id = blockIdx.x;
  const int xcd = id & 7;
  const int b = xcd >> 1;
  const int tile = ((id >> 3) << 1) + (xcd & 1);   // 0..127
  const int rowbase = tile * 32;
  const int tid = threadIdx.x;
  const int wave = tid >> 6, lane = tid & 63;
  const int l31 = lane & 31;
  const float sc = 0.088388347648318447f;  // 1/sqrt(128)
  const size_t qbase = (size_t)b * BSTRIDE + (size_t)tile * 4096 + lane * 8;
  short8 qh[8], ql[8];
  #pragma unroll
  for (int ks = 0; ks < 8; ++ks) {
    qh[ks] = *(const short8*)(QTh + qbase + ks * 512);
    ql[ks] = *(const short8*)(QTl + qbase + ks * 512);
  }
  float m = -INFINITY, l = 0.f;
  for (int ct = wave; ct < 128; ct += 4) {
    const size_t kbase = (size_t)b * BSTRIDE + (size_t)ct * 4096 + lane * 8;
    floatx16 accA, accB;
    #pragma unroll
    for (int r = 0; r < 16; ++r) { accA[r] = 0.f; accB[r] = 0.f; }
    #pragma unroll
    for (int ks = 0; ks < 4; ++ks) {
      short8 kh0 = *(const short8*)(Kh + kbase + ks * 512);
      short8 kl0 = *(const short8*)(Kl + kbase + ks * 512);
      short8 kh1 = *(const short8*)(Kh + kbase + (ks + 4) * 512);
      short8 kl1 = *(const short8*)(Kl + kbase + (ks + 4) * 512);
      accA = __builtin_amdgcn_mfma_f32_32x32x16_bf16(kh0, qh[ks], accA, 0, 0, 0);
      accB = __builtin_amdgcn_mfma_f32_32x32x16_bf16(kh1, qh[ks + 4], accB, 0, 0, 0);
      accA = __builtin_amdgcn_mfma_f32_32x32x16_bf16(kh0, ql[ks], accA, 0, 0, 0);
      accB = __builtin_amdgcn_mfma_f32_32x32x16_bf16(kh1, ql[ks + 4], accB, 0, 0, 0);
      accA = __builtin_amdgcn_mfma_f32_32x32x16_bf16(kl0, qh[ks], accA, 0, 0, 0);
      accB = __builtin_amdgcn_mfma_f32_32x32x16_bf16(kl1, qh[ks + 4], accB, 0, 0, 0);
    }
    float s[16];
    float tmax = -INFINITY;
    #pragma unroll
    for (int r = 0; r < 16; ++r) {
      s[r] = (accA[r] + accB[r]) * sc;
      tmax = fmaxf(tmax, s[r]);
    }
    const float mn = fmaxf(m, tmax);
    float ps = 0.f;
    #pragma unroll
    for (int r = 0; r < 16; ++r) ps += __expf(s[r] - mn);
    l = l * __expf(m - mn) + ps;
    m = mn;
  }
  {
    const float mo = __shfl_xor(m, 32, 64);
    const float lo = __shfl_xor(l, 32, 64);
    const float mn = fmaxf(m, mo);
    l = l * __expf(m - mn) + lo * __expf(mo - mn);
    m = mn;
  }
  if (lane < 32) { smM[wave][l31] = m; smL[wave][l31] = l; }
  __syncthreads();
  if (tid < 32) {
    float mm = smM[0][tid], ll = smL[0][tid];
    #pragma unroll
    for (int w = 1; w < 4; ++w) {
      const float mo = smM[w][tid], lo = smL[w][tid];
      const float mn = fmaxf(mm, mo);
      ll = ll * __expf(mm - mn) + lo * __expf(mo - mn);
      mm = mn;
    }
    mrow[b * SS + rowbase + tid] = mm;
    linv[b * SS + rowbase + tid] = 1.0f / ll;
  }
}

// ---------------- Kernel C2: recompute scores (identical chains), write p once, P@V -
__global__ __launch_bounds__(256, 2) void pv_kernel(const short* __restrict__ QTh,
                                                    const short* __restrict__ QTl,
                                                    const short* __restrict__ Kh,
                                                    const short* __restrict__ Kl,
                                                    const short* __restrict__ VT,
                                                    float* __restrict__ attn,
                                                    const float* __restrict__ mrow,
                                                    const float* __restrict__ linv,
                                                    float* __restrict__ outp) {
  __shared__ float sAcc[3][4][64][16];  // 48 KB partial-out exchange
  const int id = blockIdx.x;
  const int xcd = id & 7;
  const int b = xcd >> 1;
  const int tile = ((id >> 3) << 1) + (xcd & 1);   // 0..127
  const int rowbase = tile * 32;
  const int tid = threadIdx.x;
  const int wave = tid >> 6, lane = tid & 63;
  const int l31 = lane & 31, half = lane >> 5;
  const float sc = 0.088388347648318447f;
  const size_t qbase = (size_t)b * BSTRIDE + (size_t)tile * 4096 + lane * 8;
  short8 qh[8], ql[8];
  #pragma unroll
  for (int ks = 0; ks < 8; ++ks) {
    qh[ks] = *(const short8*)(QTh + qbase + ks * 512);
    ql[ks] = *(const short8*)(QTl + qbase + ks * 512);
  }
  const float m_i = mrow[b * SS + rowbase + l31];
  const float li = linv[b * SS + rowbase + l31];
  float* arow = attn + (size_t)b * SS * SS + (size_t)(rowbase + l31) * SS + 4 * half;
  const short* vtb = VT + (size_t)b * BSTRIDE + lane * 8;
  floatx16 pacc[4];
  #pragma unroll
  for (int dt = 0; dt < 4; ++dt)
    #pragma unroll
    for (int r = 0; r < 16; ++r) pacc[dt][r] = 0.f;
  for (int ct = wave; ct < 128; ct += 4) {
    const size_t kbase = (size_t)b * BSTRIDE + (size_t)ct * 4096 + lane * 8;
    floatx16 accA, accB;
    #pragma unroll
    for (int r = 0; r < 16; ++r) { accA[r] = 0.f; accB[r] = 0.f; }
    #pragma unroll
    for (int ks = 0; ks < 4; ++ks) {
      short8 kh0 = *(const short8*)(Kh + kbase + ks * 512);
      short8 kl0 = *(const short8*)(Kl + kbase + ks * 512);
      short8 kh1 = *(const short8*)(Kh + kbase + (ks + 4) * 512);
      short8 kl1 = *(const short8*)(Kl + kbase + (ks + 4) * 512);
      accA = __builtin_amdgcn_mfma_f32_32x32x16_bf16(kh0, qh[ks], accA, 0, 0, 0);
      accB = __builtin_amdgcn_mfma_f32_32x32x16_bf16(kh1, qh[ks + 4], accB, 0, 0, 0);
      accA = __builtin_amdgcn_mfma_f32_32x32x16_bf16(kh0, ql[ks], accA, 0, 0, 0);
      accB = __builtin_amdgcn_mfma_f32_32x32x16_bf16(kh1, ql[ks + 4], accB, 0, 0, 0);
      accA = __builtin_amdgcn_mfma_f32_32x32x16_bf16(kl0, qh[ks], accA, 0, 0, 0);
      accB = __builtin_amdgcn_mfma_f32_32x32x16_bf16(kl1, qh[ks + 4], accB, 0, 0, 0);
    }
    float p[16];
    #pragma unroll
    for (int r = 0; r < 16; ++r)
      p[r] = __expf((accA[r] + accB[r]) * sc - m_i) * li;
    // store p: lane owns row q=l31; regs 4g..4g+3 are t' = 8g + 4*half + 0..3
    #pragma unroll
    for (int g = 0; g < 4; ++g) {
      floatx4 o = {p[4 * g], p[4 * g + 1], p[4 * g + 2], p[4 * g + 3]};
      __builtin_nontemporal_store(o, (floatx4*)(arow + ct * 32 + 8 * g));
    }
    // C->A frags (k = t): af0 covers t'=0..15, af1 covers t'=16..31
    short8 af0, af1;
    #pragma unroll
    for (int rr = 0; rr < 4; ++rr) {
      const float shl = __shfl_xor(p[rr], 32, 64);
      const float shh = __shfl_xor(p[rr + 4], 32, 64);
      af0[rr] = f2bf(half ? shh : p[rr]);
      af0[rr + 4] = f2bf(half ? p[rr + 4] : shl);
      const float shl2 = __shfl_xor(p[rr + 8], 32, 64);
      const float shh2 = __shfl_xor(p[rr + 12], 32, 64);
      af1[rr] = f2bf(half ? shh2 : p[rr + 8]);
      af1[rr + 4] = f2bf(half ? p[rr + 12] : shl2);
    }
    #pragma unroll
    for (int dt = 0; dt < 4; ++dt) {
      short8 v0 = *(const short8*)(vtb + (size_t)(dt * 256 + ct * 2) * 512);
      pacc[dt] = __builtin_amdgcn_mfma_f32_32x32x16_bf16(af0, v0, pacc[dt], 0, 0, 0);
      short8 v1 = *(const short8*)(vtb + (size_t)(dt * 256 + ct * 2 + 1) * 512);
      pacc[dt] = __builtin_amdgcn_mfma_f32_32x32x16_bf16(af1, v1, pacc[dt], 0, 0, 0);
    }
  }
  if (wave > 0) {
    #pragma unroll
    for (int dt = 0; dt < 4; ++dt)
      #pragma unroll
      for (int r = 0; r < 16; ++r) sAcc[wave - 1][dt][lane][r] = pacc[dt][r];
  }
  __syncthreads();
  if (wave == 0) {
    #pragma unroll
    for (int dt = 0; dt < 4; ++dt)
      #pragma unroll
      for (int r = 0; r < 16; ++r) {
        const int q = (r & 3) + 8 * (r >> 2) + 4 * half;
        const float v = pacc[dt][r] + sAcc[0][dt][lane][r] + sAcc[1][dt][lane][r] +
                        sAcc[2][dt][lane][r];
        outp[((size_t)b * SS + rowbase + q) * DKk + dt * 32 + l31] = v;
      }
  }
}

extern "C" void kernel_launch(void* const* d_in, const int* in_sizes, int n_in,
                              void* d_out, int out_size, void* d_ws, size_t ws_size,
                              hipStream_t stream) {
  const float* x  = (const float*)d_in[0];
  const float* tp = (const float*)d_in[1];
  const float* Wq = (const float*)d_in[2];
  const float* bq = (const float*)d_in[3];
  const float* Wk = (const float*)d_in[4];
  const float* bk = (const float*)d_in[5];
  const float* Wv = (const float*)d_in[6];
  const float* bv = (const float*)d_in[7];
  const float* Wt = (const float*)d_in[8];
  const float* bt = (const float*)d_in[9];
  float* out  = (float*)d_out;
  float* attn = out + (size_t)BB * SS * DKk;
  float* ws = (float*)d_ws;
  float* Tws   = ws;                          // 65536
  float* bqt   = ws + 65536;                  // 512
  short* WqphF = (short*)(ws + 66048);        // 524288 shorts (4 batches)
  short* WqplF = (short*)(ws + 328192);
  short* WkhF  = (short*)(ws + 590336);       // 131072 shorts each
  short* WklF  = (short*)(ws + 655872);
  short* WvhF  = (short*)(ws + 721408);
  short* WvlF  = (short*)(ws + 786944);
  short* XAh   = (short*)(ws + 852480);       // 16777216 shorts
  short* XAl   = (short*)(ws + 9241088);
  short* QTh   = (short*)(ws + 17629696);     // 2097152 shorts each
  short* QTl   = (short*)(ws + 18678272);
  short* Kh    = (short*)(ws + 19726848);
  short* Kl    = (short*)(ws + 20775424);
  short* VT    = (short*)(ws + 21824000);
  float* mrow  = ws + 22872576;
  float* lin   = ws + 22888960;               // end 22905344 fl = 91.6 MiB

  temb_kernel<<<dim3(8, 4), 256, 0, stream>>>(tp, Wt, bt, bq, Tws, bqt);
  wqp_kernel<<<dim3(1024, 4), 128, 0, stream>>>(Wq, Tws, WqphF, WqplF);
  wcast_kernel<<<dim3(64, 2), 256, 0, stream>>>(Wk, Wv, WkhF, WklF, WvhF, WvlF);
  xcast_kernel<<<512, 256, 0, stream>>>(x, XAh, XAl);
  proj_kernel<<<1536, 256, 0, stream>>>(XAh, XAl, WqphF, WqplF, WkhF, WklF,
                                        WvhF, WvlF, bqt, bk, bv,
                                        QTh, QTl, Kh, Kl, VT);
  ml_kernel<<<512, 256, 0, stream>>>(QTh, QTl, Kh, Kl, mrow, lin);
  pv_kernel<<<512, 256, 0, stream>>>(QTh, QTl, Kh, Kl, VT, attn, mrow, lin, out);
}